// Round 4
// baseline (331.214 us; speedup 1.0000x reference)
//
#include <hip/hip_runtime.h>
#include <cmath>

// Problem constants (from reference)
#define NB 4
#define NP 8192          // 2^13 points per batch
#define NE 262144        // 2^18 edges per batch
#define NTOT (NB * NE)   // 2^20 edges total
#define NCIN 32
#define NCOUT 32
#define NH 16
#define GAMMA 4.0f

#define BINS 2048        // dst-tile bins: bin = dg>>4 (16 dst rows per bin)
#define CAP  1024        // bucket capacity (lambda=512; +22 sigma)

typedef _Float16 half8 __attribute__((ext_vector_type(8)));
typedef float floatx4 __attribute__((ext_vector_type(4)));

// ---------------------------------------------------------------------------
// R4: bucket-by-dst (kills global atomic RMW, R1 lesson) + edge-parallel
// per-edge MFMA tiles (kills serial per-edge latency chain, R3 lesson).
//   msg[e,o] = sum_k Z[e,k] Wf[k,o], k=h*32+i, Z[e,k]=rbf_h(e)*x[src_e,i]
// 16 edges per wave-tile; A-frag built in regs; W stationary in LDS;
// accumulate into 16x32 LDS out-tile via ds-atomics; one plain store per bin.
//
// ws layout: gcnt[2048] u32 @0 ; recs (u64) @8192, 2048*1024*8 = 16 MB
// rec = { bits 0..15: srcg (15b), 16..19: row (dg&15), 32..63: r (f32) }
// ---------------------------------------------------------------------------

__global__ __launch_bounds__(256)
void k_scatter(const int* __restrict__ edge_src,
               const int* __restrict__ edge_dst,
               const float* __restrict__ edge_vec,
               unsigned* __restrict__ gcnt,
               unsigned long long* __restrict__ recs)
{
    __shared__ unsigned lh[BINS];    // local hist, then absolute cursors
    const int t = threadIdx.x;
    const long e0 = (long)blockIdx.x * 4096;    // 256 blocks x 4096 edges

    for (int b = t; b < BINS; b += 256) lh[b] = 0;
    __syncthreads();

    int dgs[16];
    #pragma unroll
    for (int j = 0; j < 16; ++j) {
        const long e = e0 + j * 256 + t;
        const int bb = (int)(e >> 18);
        const int dg = (bb << 13) + edge_dst[e];
        dgs[j] = dg;
        atomicAdd(&lh[dg >> 4], 1u);
    }
    __syncthreads();

    // one global atomic per nonzero bin per block (~1771 of 2048)
    for (int b = t; b < BINS; b += 256) {
        const unsigned c = lh[b];
        unsigned base = 0;
        if (c) base = atomicAdd(&gcnt[b], c);
        lh[b] = (unsigned)b * CAP + base;       // absolute cursor
    }
    __syncthreads();

    #pragma unroll
    for (int j = 0; j < 16; ++j) {
        const long e = e0 + j * 256 + t;
        const int dg = dgs[j];
        const int bin = dg >> 4;
        const int bb = (int)(e >> 18);
        const int sg = (bb << 13) + edge_src[e];
        const float vx = edge_vec[3 * e + 0];
        const float vy = edge_vec[3 * e + 1];
        const float vz = edge_vec[3 * e + 2];
        // ref's self-interaction zeroing (r<1e-10 -> vec=0) is a numeric no-op
        const float r = sqrtf(vx * vx + vy * vy + vz * vz);
        const unsigned slot = atomicAdd(&lh[bin], 1u);
        if (slot < (unsigned)bin * CAP + CAP) {
            const unsigned lo = (unsigned)sg | ((unsigned)(dg & 15) << 16);
            recs[slot] = ((unsigned long long)__float_as_uint(r) << 32) | lo;
        }
    }
}

// One block per bin. LDS: wsw 32 KB + outacc 2.1 KB -> 4 blocks/CU.
// MFMA f32_16x16x32_f16 layouts (HW-verified, learn_hip m89/m91):
//   A: lane holds A[m=lane&15][k = (lane>>4)*8 + j], j=0..7
//   B: lane holds B[k = (lane>>4)*8 + j][n = lane&15]
//   D: lane holds D[row=(lane>>4)*4 + rr][col = lane&15], rr=0..3
// k = s*32 + q*8 + j  =>  h = s, i = q*8+j: A-frag = rbf_s(edge m)*x[m][q*8+j]
__global__ __launch_bounds__(256, 4)
void k_bin(const float* __restrict__ features,
           const float* __restrict__ Wg,
           const float* __restrict__ mu_g,
           const unsigned* __restrict__ gcnt,
           const unsigned long long* __restrict__ recs,
           const int* __restrict__ n_norm_p,
           float* __restrict__ out)
{
    // W in exact B-frag order: wsw[((s*2+u)*64+lane)*8+j] = W[s][(lane&15)+16u][(lane>>4)*8+j]
    __shared__ _Float16 wsw[16 * 2 * 64 * 8];   // 32 KB, b128 reads conflict-free (R1: 0 conflicts)
    __shared__ float outacc[16 * 33];           // stride 33: row-stride !≡ 0 mod 32
    __shared__ float mus[16];

    const int t = threadIdx.x;
    for (int idx = t; idx < 16384; idx += 256) {
        int j = idx & 7;
        int l = (idx >> 3) & 63;
        int u = (idx >> 9) & 1;
        int s = idx >> 10;
        int n = (l & 15) + (u << 4);
        int i = ((l >> 4) << 3) | j;
        wsw[idx] = (_Float16)Wg[(s * NCOUT + n) * NCIN + i];
    }
    for (int i = t; i < 16 * 33; i += 256) outacc[i] = 0.f;
    if (t < 16) mus[t] = mu_g[t];
    __syncthreads();

    const int lane = t & 63;
    const int wv   = t >> 6;
    const int m    = lane & 15;
    const int q    = lane >> 4;
    const int bin  = blockIdx.x;

    int n = (int)gcnt[bin];
    if (n > CAP) n = CAP;
    const long bbase = (long)bin * CAP;

    const int ntiles = (n + 15) >> 4;
    for (int tile = wv; tile < ntiles; tile += 4) {
        int ei = tile * 16 + m;
        const bool valid = (ei < n);
        if (!valid) ei = n - 1;                  // safe: ntiles>0 => n>=1
        const unsigned long long rc = recs[bbase + ei];
        const int   sg  = (int)(rc & 0xFFFFu);
        const int   row = (int)((rc >> 16) & 15u);
        const float r   = __uint_as_float((unsigned)(rc >> 32));

        // full feature row of edge m fetched across q: 2x16B per lane
        const floatx4* xp = (const floatx4*)(features + ((long)sg << 5) + q * 8);
        const floatx4 xa = xp[0], xb = xp[1];
        half8 xh;
        xh[0] = (_Float16)xa[0]; xh[1] = (_Float16)xa[1];
        xh[2] = (_Float16)xa[2]; xh[3] = (_Float16)xa[3];
        xh[4] = (_Float16)xb[0]; xh[5] = (_Float16)xb[1];
        xh[6] = (_Float16)xb[2]; xh[7] = (_Float16)xb[3];

        float rbf[16];
        #pragma unroll
        for (int s = 0; s < 16; ++s) {
            const float d = r - mus[s];
            rbf[s] = valid ? __expf(-GAMMA * d * d) : 0.f;   // invalid lanes: A=0
        }

        floatx4 accLo = {0.f, 0.f, 0.f, 0.f};
        floatx4 accHi = {0.f, 0.f, 0.f, 0.f};
        #pragma unroll
        for (int s = 0; s < 16; ++s) {
            const _Float16 rb = (_Float16)rbf[s];
            half8 a = {rb, rb, rb, rb, rb, rb, rb, rb};
            a *= xh;                                          // 4x v_pk_mul_f16
            half8 b0 = *(const half8*)(wsw + ((s * 2 + 0) * 64 + lane) * 8);
            half8 b1 = *(const half8*)(wsw + ((s * 2 + 1) * 64 + lane) * 8);
            accLo = __builtin_amdgcn_mfma_f32_16x16x32_f16(a, b0, accLo, 0, 0, 0);
            accHi = __builtin_amdgcn_mfma_f32_16x16x32_f16(a, b1, accHi, 0, 0, 0);
        }

        // D[row'=q*4+rr][col=m]; edge (q*4+rr)'s out-row via shfl from its lane.
        // Invalid edges contribute exact zeros to a clamped (valid) row.
        #pragma unroll
        for (int rr = 0; rr < 4; ++rr) {
            const int rowr = __shfl(row, q * 4 + rr, 64);
            atomicAdd(&outacc[rowr * 33 + m],      accLo[rr]);
            atomicAdd(&outacc[rowr * 33 + m + 16], accHi[rr]);
        }
    }
    __syncthreads();

    const int nn = n_norm_p[0];
    const float scale = (nn > 0) ? rsqrtf((float)nn) : 1.0f;
    // each out element written exactly once across the grid -> no memset, no atomics
    for (int i = t; i < 512; i += 256) {
        const int row = i >> 5, ch = i & 31;
        out[((long)bin * 16 + row) * NCOUT + ch] = outacc[row * 33 + ch] * scale;
    }
}

extern "C" void kernel_launch(void* const* d_in, const int* in_sizes, int n_in,
                              void* d_out, int out_size, void* d_ws, size_t ws_size,
                              hipStream_t stream) {
    const float* features = (const float*)d_in[0];
    const float* edge_vec = (const float*)d_in[1];
    const float* W        = (const float*)d_in[2];
    const float* mu       = (const float*)d_in[3];
    const int*   edge_src = (const int*)d_in[4];
    const int*   edge_dst = (const int*)d_in[5];
    const int*   n_norm   = (const int*)d_in[6];
    float* out = (float*)d_out;

    unsigned* gcnt = (unsigned*)d_ws;
    unsigned long long* recs = (unsigned long long*)((char*)d_ws + 8192);

    hipMemsetAsync(gcnt, 0, BINS * sizeof(unsigned), stream);
    k_scatter<<<256, 256, 0, stream>>>(edge_src, edge_dst, edge_vec, gcnt, recs);
    k_bin<<<BINS, 256, 0, stream>>>(features, W, mu, gcnt, recs, n_norm, out);
}

// Round 5
// 298.019 us; speedup vs baseline: 1.1114x; 1.1114x over previous
//
#include <hip/hip_runtime.h>
#include <cmath>

// Problem constants (from reference)
#define NB 4
#define NP 8192          // 2^13 points per batch
#define NE 262144        // 2^18 edges per batch
#define NTOT (NB * NE)   // 2^20 edges total
#define NCIN 32
#define NCOUT 32
#define NH 16
#define GAMMA 4.0f

#define BINS 2048        // dst-tile bins: bin = dg>>4 (16 dst rows per bin)
#define CAP  1024        // bucket capacity (lambda=512; +22 sigma)

typedef _Float16 half8 __attribute__((ext_vector_type(8)));
typedef float floatx4 __attribute__((ext_vector_type(4)));

// ---------------------------------------------------------------------------
// R5 = R4 (edge-parallel MFMA, bucket-by-dst, LDS out-tile, zero out-atomics)
//    + R3's memory discipline: bulk-stage the record bucket into LDS BEFORE the
//      gather phase (R3 measured: phase separation keeps features L2-resident,
//      FETCH 20 MB; R4's interleaved recs stream evicted them, FETCH 533 MB)
//    + f16 feature pre-convert: 64 B rows (one sector), 2 MB L2-resident.
//
// ws layout: gcnt[2048] u32 @0 ; recs u64 @8192 (16 MB) ; xf16 @8192+16M (2 MB)
// rec = { bits 0..15: srcg (15b), 16..19: row (dg&15), 32..63: r (f32) }
// ---------------------------------------------------------------------------

__global__ __launch_bounds__(256)
void k_cvt(const float* __restrict__ features, _Float16* __restrict__ xf16) {
    const int i = blockIdx.x * 256 + threadIdx.x;   // 1024 blocks: 2^20 elems / 4
    const floatx4 v = ((const floatx4*)features)[i];
    half8* dst = (half8*)xf16;
    _Float16 h0 = (_Float16)v[0], h1 = (_Float16)v[1];
    _Float16 h2 = (_Float16)v[2], h3 = (_Float16)v[3];
    // pack 4 halves; write 8 B per thread, coalesced
    ((ushort1*)0, 0);  // no-op
    unsigned short u0 = __builtin_bit_cast(unsigned short, h0);
    unsigned short u1 = __builtin_bit_cast(unsigned short, h1);
    unsigned short u2 = __builtin_bit_cast(unsigned short, h2);
    unsigned short u3 = __builtin_bit_cast(unsigned short, h3);
    ushort4 pk; pk.x = u0; pk.y = u1; pk.z = u2; pk.w = u3;
    ((ushort4*)xf16)[i] = pk;
}

__global__ __launch_bounds__(256)
void k_scatter(const int* __restrict__ edge_src,
               const int* __restrict__ edge_dst,
               const float* __restrict__ edge_vec,
               unsigned* __restrict__ gcnt,
               unsigned long long* __restrict__ recs)
{
    __shared__ unsigned lh[BINS];    // local hist, then absolute cursors
    const int t = threadIdx.x;
    const long e0 = (long)blockIdx.x * 4096;    // 256 blocks x 4096 edges

    for (int b = t; b < BINS; b += 256) lh[b] = 0;
    __syncthreads();

    int dgs[16];
    #pragma unroll
    for (int j = 0; j < 16; ++j) {
        const long e = e0 + j * 256 + t;
        const int bb = (int)(e >> 18);
        const int dg = (bb << 13) + edge_dst[e];
        dgs[j] = dg;
        atomicAdd(&lh[dg >> 4], 1u);
    }
    __syncthreads();

    // one global atomic per nonzero bin per block (~1771 of 2048)
    for (int b = t; b < BINS; b += 256) {
        const unsigned c = lh[b];
        unsigned base = 0;
        if (c) base = atomicAdd(&gcnt[b], c);
        lh[b] = (unsigned)b * CAP + base;       // absolute cursor
    }
    __syncthreads();

    #pragma unroll
    for (int j = 0; j < 16; ++j) {
        const long e = e0 + j * 256 + t;
        const int dg = dgs[j];
        const int bin = dg >> 4;
        const int bb = (int)(e >> 18);
        const int sg = (bb << 13) + edge_src[e];
        const float vx = edge_vec[3 * e + 0];
        const float vy = edge_vec[3 * e + 1];
        const float vz = edge_vec[3 * e + 2];
        // ref's self-interaction zeroing (r<1e-10 -> vec=0) is a numeric no-op
        const float r = sqrtf(vx * vx + vy * vy + vz * vz);
        const unsigned slot = atomicAdd(&lh[bin], 1u);
        if (slot < (unsigned)bin * CAP + CAP) {
            const unsigned lo = (unsigned)sg | ((unsigned)(dg & 15) << 16);
            recs[slot] = ((unsigned long long)__float_as_uint(r) << 32) | lo;
        }
    }
}

// One block per bin. LDS: wsw 32K + raw 8K + outacc 2.1K -> 3 blocks/CU.
// MFMA f32_16x16x32_f16 layouts (HW-verified, learn_hip m89/m91):
//   A: lane holds A[m=lane&15][k = (lane>>4)*8 + j], j=0..7
//   B: lane holds B[k = (lane>>4)*8 + j][n = lane&15]
//   D: lane holds D[row=(lane>>4)*4 + rr][col = lane&15], rr=0..3
// k = s*32 + q*8 + j  =>  h = s, i = q*8+j: A-frag = rbf_s(edge m)*x[m][q*8+j]
__global__ __launch_bounds__(256)
void k_bin(const _Float16* __restrict__ xf16,
           const float* __restrict__ Wg,
           const float* __restrict__ mu_g,
           const unsigned* __restrict__ gcnt,
           const unsigned long long* __restrict__ recs,
           const int* __restrict__ n_norm_p,
           float* __restrict__ out)
{
    // W in exact B-frag order: wsw[((s*2+u)*64+lane)*8+j] = W[s][(lane&15)+16u][(lane>>4)*8+j]
    __shared__ _Float16 wsw[16 * 2 * 64 * 8];   // 32 KB, b128 reads conflict-free
    __shared__ unsigned long long raw[CAP];     // 8 KB staged records (phase separation)
    __shared__ float outacc[16 * 33];           // stride 33: row-stride !≡ 0 mod 32
    __shared__ float mus[16];

    const int t = threadIdx.x;
    const int bin = blockIdx.x;

    int n = (int)gcnt[bin];
    if (n > CAP) n = CAP;

    for (int idx = t; idx < 16384; idx += 256) {
        int j = idx & 7;
        int l = (idx >> 3) & 63;
        int u = (idx >> 9) & 1;
        int s = idx >> 10;
        int nn = (l & 15) + (u << 4);
        int i = ((l >> 4) << 3) | j;
        wsw[idx] = (_Float16)Wg[(s * NCOUT + nn) * NCIN + i];
    }
    // bulk coalesced stage of the record bucket (the ONLY recs traffic)
    for (int i = t; i < n; i += 256) raw[i] = recs[(long)bin * CAP + i];
    for (int i = t; i < 16 * 33; i += 256) outacc[i] = 0.f;
    if (t < 16) mus[t] = mu_g[t];
    __syncthreads();

    const int lane = t & 63;
    const int wv   = t >> 6;
    const int m    = lane & 15;
    const int q    = lane >> 4;

    const int ntiles = (n + 15) >> 4;
    for (int tile = wv; tile < ntiles; tile += 4) {
        int ei = tile * 16 + m;
        const bool valid = (ei < n);
        if (!valid) ei = n - 1;                  // safe: ntiles>0 => n>=1
        const unsigned long long rc = raw[ei];   // LDS, same-addr broadcast across q
        const int   sg  = (int)(rc & 0xFFFFu);
        const int   row = (int)((rc >> 16) & 15u);
        const float r   = __uint_as_float((unsigned)(rc >> 32));

        // f16 feature row: 64 B, lane reads contiguous 16 B (one sector per row)
        const half8 xh = *(const half8*)(xf16 + ((long)sg << 5) + q * 8);

        float rbf[16];
        #pragma unroll
        for (int s = 0; s < 16; ++s) {
            const float d = r - mus[s];
            rbf[s] = valid ? __expf(-GAMMA * d * d) : 0.f;   // invalid lanes: A=0
        }

        floatx4 accLo = {0.f, 0.f, 0.f, 0.f};
        floatx4 accHi = {0.f, 0.f, 0.f, 0.f};
        #pragma unroll
        for (int s = 0; s < 16; ++s) {
            const _Float16 rb = (_Float16)rbf[s];
            half8 a = {rb, rb, rb, rb, rb, rb, rb, rb};
            a *= xh;                                          // 4x v_pk_mul_f16
            half8 b0 = *(const half8*)(wsw + ((s * 2 + 0) * 64 + lane) * 8);
            half8 b1 = *(const half8*)(wsw + ((s * 2 + 1) * 64 + lane) * 8);
            accLo = __builtin_amdgcn_mfma_f32_16x16x32_f16(a, b0, accLo, 0, 0, 0);
            accHi = __builtin_amdgcn_mfma_f32_16x16x32_f16(a, b1, accHi, 0, 0, 0);
        }

        // D[row'=q*4+rr][col=m]; edge (q*4+rr)'s out-row via shfl from its lane.
        // Invalid edges contribute exact zeros to a clamped (valid) row.
        #pragma unroll
        for (int rr = 0; rr < 4; ++rr) {
            const int rowr = __shfl(row, q * 4 + rr, 64);
            atomicAdd(&outacc[rowr * 33 + m],      accLo[rr]);
            atomicAdd(&outacc[rowr * 33 + m + 16], accHi[rr]);
        }
    }
    __syncthreads();

    const int nn = n_norm_p[0];
    const float scale = (nn > 0) ? rsqrtf((float)nn) : 1.0f;
    // each out element written exactly once across the grid -> no memset, no atomics
    for (int i = t; i < 512; i += 256) {
        const int row = i >> 5, ch = i & 31;
        out[((long)bin * 16 + row) * NCOUT + ch] = outacc[row * 33 + ch] * scale;
    }
}

extern "C" void kernel_launch(void* const* d_in, const int* in_sizes, int n_in,
                              void* d_out, int out_size, void* d_ws, size_t ws_size,
                              hipStream_t stream) {
    const float* features = (const float*)d_in[0];
    const float* edge_vec = (const float*)d_in[1];
    const float* W        = (const float*)d_in[2];
    const float* mu       = (const float*)d_in[3];
    const int*   edge_src = (const int*)d_in[4];
    const int*   edge_dst = (const int*)d_in[5];
    const int*   n_norm   = (const int*)d_in[6];
    float* out = (float*)d_out;

    unsigned* gcnt = (unsigned*)d_ws;
    unsigned long long* recs = (unsigned long long*)((char*)d_ws + 8192);
    _Float16* xf16 = (_Float16*)((char*)d_ws + 8192 + (size_t)BINS * CAP * 8);

    hipMemsetAsync(gcnt, 0, BINS * sizeof(unsigned), stream);
    k_cvt    <<<NTOT / 1024, 256, 0, stream>>>(features, xf16);
    k_scatter<<<256, 256, 0, stream>>>(edge_src, edge_dst, edge_vec, gcnt, recs);
    k_bin    <<<BINS, 256, 0, stream>>>(xf16, W, mu, gcnt, recs, n_norm, out);
}